// Round 1
// baseline (232.060 us; speedup 1.0000x reference)
//
#include <hip/hip_runtime.h>
#include <hip/hip_bf16.h>
#include <stdint.h>

#define NR 384          // total rows
#define DD 73728        // C*H*W
#define PDV 16          // N_PARTS * N_DATASETS
#define BSV 192         // batch size
#define KSPLIT 128      // split-K factor (768 gram blocks = 3/CU)
#define KCH 576         // DD / KSPLIT
#define BK 32           // K per MFMA step
#define NIT 18          // KCH / BK
#define KCTOT 2304      // DD / 32  (number of 32-wide k-chunks)
#define ZROW 32         // bf16 elems per (row, k-chunk) fragment = 64 B
#define ZKC (NR * ZROW) // 12288 elems per k-chunk plane

typedef __bf16 bf16;
typedef __attribute__((ext_vector_type(8))) __bf16 bf16x8;
typedef __attribute__((ext_vector_type(4))) float f32x4;

// ---------------------------------------------------------------- kernel 0
// Demean + cast to bf16 ONCE (X was previously re-read 3x as f32 by k_gram).
// Zt layout is gram-native: Zt[kc][row][kk], kc=k/32, kk=k%32 -> each
// (row,kc) fragment is 64 B = one cache line, so gram's MFMA fragment loads
// are full-line transactions with no LDS staging needed.
__global__ __launch_bounds__(256) void k_prep(const float* __restrict__ X,
                                              const float* __restrict__ M,
                                              bf16* __restrict__ Zt) {
    const int r   = blockIdx.x >> 2;     // 384 rows x 4 segments
    const int seg = blockIdx.x & 3;
    const int ds  = (r >> 2) & 3;        // dataset id = (r/4)%4
    const float* xr = X + (size_t)r * DD;
    const float* mr = M + (size_t)ds * DD;
    bf16* zr = Zt + (size_t)r * ZROW;
#pragma unroll 3
    for (int i = 0; i < 9; ++i) {        // 9216 chunks/row / 4 seg / 256 thr
        int c = seg * 2304 + i * 256 + threadIdx.x;
        int k = c * 8;
        float4 x0 = *(const float4*)(xr + k);
        float4 x1 = *(const float4*)(xr + k + 4);
        float4 m0 = *(const float4*)(mr + k);
        float4 m1 = *(const float4*)(mr + k + 4);
        bf16x8 z;
        z[0] = (bf16)(x0.x - m0.x); z[1] = (bf16)(x0.y - m0.y);
        z[2] = (bf16)(x0.z - m0.z); z[3] = (bf16)(x0.w - m0.w);
        z[4] = (bf16)(x1.x - m1.x); z[5] = (bf16)(x1.y - m1.y);
        z[6] = (bf16)(x1.z - m1.z); z[7] = (bf16)(x1.w - m1.w);
        *(bf16x8*)(zr + (size_t)(k >> 5) * ZKC + (k & 31)) = z;
    }
}

// ---------------------------------------------------------------- kernel 1
// Partial Gram, NO LDS: MFMA fragments load straight from Zt. A wave's
// fragment = 16 rows (l15) x 16 B (quad) -> 4 lanes per 64-B line, every
// line fully consumed. Zt (56.6 MB) is L3-resident (written by k_prep), A/B
// panel overlap across waves hits L1/L2. No barriers, no demean VALU, no
// ds round-trip -> pure VMEM||MFMA pipeline the compiler can schedule.
// Accumulation order per (tile,ks) is bit-identical to the previous kernel.
__global__ __launch_bounds__(256, 3) void k_gram(const bf16* __restrict__ Zt,
                                                 float* __restrict__ Gp) {
    const int tid  = threadIdx.x;
    const int lane = tid & 63;
    const int w    = tid >> 6;
    const int quad = lane >> 4;
    const int l15  = lane & 15;
    const int wm   = w & 1, wn = w >> 1;

    int xcd  = blockIdx.x & 7;
    int g    = blockIdx.x >> 3;
    int tile = g % 6;
    int ks   = xcd + 8 * (g / 6);        // 6 tiles of one ks share an XCD
    int tm = (tile < 3) ? 0 : ((tile < 5) ? 1 : 2);
    int tn = (tile < 3) ? tile : ((tile < 5) ? (tile - 2) : 2);

    const bf16* pa = Zt + (size_t)(ks * NIT) * ZKC
                   + (size_t)(tm * 128 + wm * 64 + l15) * ZROW + quad * 8;
    const bf16* pb = Zt + (size_t)(ks * NIT) * ZKC
                   + (size_t)(tn * 128 + wn * 64 + l15) * ZROW + quad * 8;

    f32x4 acc[4][4];
#pragma unroll
    for (int i = 0; i < 4; ++i)
#pragma unroll
        for (int j = 0; j < 4; ++j) acc[i][j] = (f32x4){0.f, 0.f, 0.f, 0.f};

    bf16x8 a0[4], b0[4], a1[4], b1[4];
    auto LDF = [&](bf16x8 (&A)[4], bf16x8 (&B)[4], int it) {
        const bf16* qa = pa + (size_t)it * ZKC;
        const bf16* qb = pb + (size_t)it * ZKC;
#pragma unroll
        for (int i = 0; i < 4; ++i) A[i] = *(const bf16x8*)(qa + i * 512);
#pragma unroll
        for (int j = 0; j < 4; ++j) B[j] = *(const bf16x8*)(qb + j * 512);
    };
    auto MM = [&](bf16x8 (&A)[4], bf16x8 (&B)[4]) {
#pragma unroll
        for (int i = 0; i < 4; ++i)
#pragma unroll
            for (int j = 0; j < 4; ++j)
                acc[i][j] = __builtin_amdgcn_mfma_f32_16x16x32_bf16(
                    A[i], B[j], acc[i][j], 0, 0, 0);
    };

    LDF(a0, b0, 0);
#pragma unroll
    for (int h = 0; h < 9; ++h) {        // 2 k-steps per h, static ping-pong
        LDF(a1, b1, 2 * h + 1);
        MM(a0, b0);
        if (h < 8) LDF(a0, b0, 2 * h + 2);
        MM(a1, b1);
    }

    float* gp = Gp + ((size_t)(ks * 6 + tile) << 14);
#pragma unroll
    for (int i = 0; i < 4; ++i) {
        int lr0 = wm * 64 + i * 16 + quad * 4;
#pragma unroll
        for (int j = 0; j < 4; ++j) {
            int lc = wn * 64 + j * 16 + l15;
#pragma unroll
            for (int r = 0; r < 4; ++r)
                gp[(lr0 + r) * 128 + lc] = acc[i][j][r];
        }
    }
}

// ---------------------------------------------------------------- kernel 2
// Reduce partials -> full symmetric G + per-row inverse norm.
__global__ __launch_bounds__(256) void k_red(const float* __restrict__ Gp,
                                             float* __restrict__ G,
                                             float* __restrict__ invn) {
    int t    = blockIdx.x * 256 + threadIdx.x;
    int tile = t >> 14;
    int idx  = t & 16383;
    int lr   = idx >> 7, lc = idx & 127;
    const float* p = Gp + ((size_t)tile << 14) + idx;
    float s = 0.0f;
#pragma unroll 8
    for (int ks = 0; ks < KSPLIT; ++ks) s += p[(size_t)ks * 98304];
    int tm = (tile < 3) ? 0 : ((tile < 5) ? 1 : 2);
    int tn = (tile < 3) ? tile : ((tile < 5) ? (tile - 2) : 2);
    int a = tm * 128 + lr, b = tn * 128 + lc;
    G[(size_t)a * NR + b] = s;
    G[(size_t)b * NR + a] = s;
    if (a == b) invn[a] = 1.0f / fmaxf(sqrtf(s), 1e-6f);
}

// ---------------------------------------------------------------- kernel 3
// One wave per row a: Ds[a] then this row's 4 pair-slot terms. NO atomics:
// the previous version ended with 384 same-address device-scope atomicAdds
// (serialized RMWs ~100-200 ns each). Write rt[a] instead; k_fin reduces.
__global__ __launch_bounds__(256) void k_dsum(const float* __restrict__ G,
                                              const float* __restrict__ invn,
                                              float* __restrict__ rt) {
    const int lane = threadIdx.x & 63;
    const int a    = blockIdx.x * 4 + (threadIdx.x >> 6);
    float ia  = invn[a];
    int arem  = a & 15;
    float acc = 0.0f;
    for (int b = lane; b < NR; b += 64) {
        float s = G[(size_t)a * NR + b] * ia * invn[b] * 10.0f;
        if ((b & 15) != arem) acc += expf(s);
    }
#pragma unroll
    for (int o = 32; o > 0; o >>= 1) acc += __shfl_down(acc, o);
    if (lane == 0) {
        float Dsa = acc;
        int pr[4];
        if (a < 16)       { pr[0] = 192 + a; pr[1] = a + 16;  pr[2] = a + 192; pr[3] = a + 368; }
        else if (a < 192) { pr[0] = 192 + a; pr[1] = a + 16;  pr[2] = a + 192; pr[3] = a - 16; }
        else if (a < 368) { pr[0] = a - 192; pr[1] = a + 16;  pr[2] = a - 192; pr[3] = a - 16; }
        else              { pr[0] = a - 192; pr[1] = a - 368; pr[2] = a - 192; pr[3] = a - 16; }
        float t = 0.0f;
#pragma unroll
        for (int s = 0; s < 4; ++s) {
            int b = pr[s];
            float num = G[(size_t)a * NR + b] * ia * invn[b] * 10.0f;
            t += -num + logf(expf(num) + Dsa);
        }
        rt[a] = t;
    }
}

// ---------------------------------------------------------------- kernel 4
// Single block: sum the 384 per-row terms -> out.
__global__ __launch_bounds__(256) void k_fin(const float* __restrict__ rt,
                                             float* __restrict__ out) {
    const int tid  = threadIdx.x;
    const int lane = tid & 63;
    const int w    = tid >> 6;
    float s = rt[tid] + ((tid < NR - 256) ? rt[256 + tid] : 0.0f);
#pragma unroll
    for (int o = 32; o > 0; o >>= 1) s += __shfl_down(s, o);
    __shared__ float ps[4];
    if (lane == 0) ps[w] = s;
    __syncthreads();
    if (tid == 0)
        out[0] = (ps[0] + ps[1] + ps[2] + ps[3]) * (1.0f / 576.0f);
}

// ---------------------------------------------------------------- launch
extern "C" void kernel_launch(void* const* d_in, const int* in_sizes, int n_in,
                              void* d_out, int out_size, void* d_ws, size_t ws_size,
                              hipStream_t stream) {
    const float* X = (const float*)d_in[0];
    const float* M = (const float*)d_in[1];
    float* out = (float*)d_out;

    char* ws = (char*)d_ws;
    float* Gp   = (float*)ws;                                  // 50.3 MB
    bf16*  Zt   = (bf16*)(ws + (size_t)KSPLIT * 6 * 16384 * 4);// 56.6 MB
    float* G    = (float*)((char*)Zt + (size_t)KCTOT * ZKC * 2);// 590 KB
    float* invn = G + (size_t)NR * NR;
    float* rt   = invn + NR;

    k_prep<<<dim3(NR * 4), dim3(256), 0, stream>>>(X, M, Zt);
    k_gram<<<dim3(6 * KSPLIT), dim3(256), 0, stream>>>(Zt, Gp);
    k_red<<<dim3(384), dim3(256), 0, stream>>>(Gp, G, invn);
    k_dsum<<<dim3(NR / 4), dim3(256), 0, stream>>>(G, invn, rt);
    k_fin<<<dim3(1), dim3(256), 0, stream>>>(rt, out);
}

// Round 2
// 205.073 us; speedup vs baseline: 1.1316x; 1.1316x over previous
//
#include <hip/hip_runtime.h>
#include <hip/hip_bf16.h>
#include <stdint.h>

#define NR 384          // total rows
#define DD 73728        // C*H*W
#define PDV 16          // N_PARTS * N_DATASETS
#define KSPLIT 128      // split-K factor (768 gram blocks = 3/CU, fully resident)
#define KCH 576         // DD / KSPLIT
#define BK 32           // K-tile per iteration
#define NIT 18          // KCH / BK
#define RS 40           // LDS row stride bf16 (80 B = 20 banks, 16B-aligned)
#define TILE_F 16384    // 128*128 floats per tile
#define KSTRIDE (9 * TILE_F)   // floats per ks in Gp9

typedef __bf16 bf16;
typedef __attribute__((ext_vector_type(4))) __bf16 bf16x4;
typedef __attribute__((ext_vector_type(8))) __bf16 bf16x8;
typedef __attribute__((ext_vector_type(4))) float f32x4;

// ---------------------------------------------------------------- kernel 1
// Fused demean + cast + partial Gram (verified round-0 main loop).
// New epilogue: writes into a 9-tile buffer Gp9[ks][pa*3+pb][128][128] --
// off-diag tiles are written BOTH orientations (transposed copy staged
// through padded LDS so both LDS reads and global stores are conflict-free/
// coalesced). Diag blocks also emit per-row norm^2 partials Dp[ks][row].
// This lets the single tail kernel read every partial it needs fully
// coalesced, eliminating k_red / k_dsum / k_fin (launch gaps were a large
// fraction of round-1's 232 us; no single kernel exceeded 71 us).
__global__ __launch_bounds__(256, 3) void k_gram(const float* __restrict__ X,
                                                 const float* __restrict__ M,
                                                 float* __restrict__ Gp9,
                                                 float* __restrict__ Dp,
                                                 unsigned* __restrict__ ctr) {
    __shared__ float msh[4 * KCH];                 // 9.2 KB
    __shared__ __align__(16) char sbuf[41984];     // ash/bsh dbuf, reused as tbuf
    bf16* ash = (bf16*)sbuf;                       // [2][128*RS]
    bf16* bsh = (bf16*)(sbuf + 20480);             // [2][128*RS]

    const int tid  = threadIdx.x;
    const int lane = tid & 63;
    const int w    = tid >> 6;
    const int quad = lane >> 4;
    const int l15  = lane & 15;
    const int wm   = w & 1, wn = w >> 1;
    const int srow = tid >> 3;           // staging row base 0..31
    const int fseg = tid & 7;            // 16B segment within 128B row-chunk
    const int mds  = (srow >> 2) & 3;    // dataset id (same for all p)

    if (blockIdx.x == 0 && tid == 0) *ctr = 0u;    // tail completion counter

    int xcd  = blockIdx.x & 7;
    int g    = blockIdx.x >> 3;
    int tile = g % 6;
    int ks   = xcd + 8 * (g / 6);        // 6 tiles of one ks share an XCD
    int tm = (tile < 3) ? 0 : ((tile < 5) ? 1 : 2);
    int tn = (tile < 3) ? tile : ((tile < 5) ? (tile - 2) : 2);
    const bool diag = (tm == tn);
    const float* Xa = X + (size_t)(tm * 128) * DD;
    const float* Xb = X + (size_t)(tn * 128) * DD;
    size_t k0 = (size_t)ks * KCH;

    // ---- stage M slice once: 4 datasets x 576 floats
    for (int i = tid; i < 4 * 144; i += 256) {
        int ds = i / 144;
        int c  = (i - ds * 144) * 4;
        *(float4*)&msh[ds * KCH + c] = *(const float4*)(M + (size_t)ds * DD + k0 + c);
    }

    f32x4 acc[4][4];
#pragma unroll
    for (int i = 0; i < 4; ++i)
#pragma unroll
        for (int j = 0; j < 4; ++j) acc[i][j] = (f32x4){0.f, 0.f, 0.f, 0.f};

    float4 xa[4], xb[4];                 // single register buffer
    auto load_regs = [&](int it) {
        size_t gk = k0 + (size_t)it * BK + fseg * 4;
#pragma unroll
        for (int p = 0; p < 4; ++p) {
            int row = p * 32 + srow;
            xa[p] = *(const float4*)(Xa + (size_t)row * DD + gk);
            if (!diag) xb[p] = *(const float4*)(Xb + (size_t)row * DD + gk);
        }
    };
    auto write_tiles = [&](int it, int buf) {
        int kc = it * BK + fseg * 4;
        float4 m4 = *(const float4*)&msh[mds * KCH + kc];   // ONE read, all p
#pragma unroll
        for (int p = 0; p < 4; ++p) {
            int row = p * 32 + srow;
            bf16x4 za;
            za[0] = (bf16)(xa[p].x - m4.x); za[1] = (bf16)(xa[p].y - m4.y);
            za[2] = (bf16)(xa[p].z - m4.z); za[3] = (bf16)(xa[p].w - m4.w);
            *(bf16x4*)&ash[buf * 5120 + row * RS + fseg * 4] = za;
            if (!diag) {
                bf16x4 zb;
                zb[0] = (bf16)(xb[p].x - m4.x); zb[1] = (bf16)(xb[p].y - m4.y);
                zb[2] = (bf16)(xb[p].z - m4.z); zb[3] = (bf16)(xb[p].w - m4.w);
                *(bf16x4*)&bsh[buf * 5120 + row * RS + fseg * 4] = zb;
            }
        }
    };
    auto compute = [&](int buf) {
        const bf16* bb = diag ? (ash + buf * 5120) : (bsh + buf * 5120);
        bf16x8 af[4], bfv[4];
#pragma unroll
        for (int i = 0; i < 4; ++i) {
            int r = wm * 64 + i * 16 + l15;
            af[i] = *(const bf16x8*)&ash[buf * 5120 + r * RS + quad * 8];
        }
#pragma unroll
        for (int j = 0; j < 4; ++j) {
            int r = wn * 64 + j * 16 + l15;
            bfv[j] = *(const bf16x8*)&bb[r * RS + quad * 8];
        }
#pragma unroll
        for (int i = 0; i < 4; ++i)
#pragma unroll
            for (int j = 0; j < 4; ++j)
                acc[i][j] = __builtin_amdgcn_mfma_f32_16x16x32_bf16(
                    af[i], bfv[j], acc[i][j], 0, 0, 0);
    };

    load_regs(0);
    __syncthreads();              // msh visible
    write_tiles(0, 0);            // vmcnt drains load(0) only
    load_regs(1);
    __syncthreads();              // L[0] published

    for (int it = 0; it < NIT; ++it) {
        int buf = it & 1;
        if (it + 1 < NIT) {
            write_tiles(it + 1, buf ^ 1);    // overlaps compute below
            if (it + 2 < NIT) load_regs(it + 2);
        }
        compute(buf);
        __syncthreads();          // publishes L[buf^1]; frees L[buf]
    }

    // ---- epilogue 1: normal-orientation tile (coalesced, from regs)
    float* gp = Gp9 + (size_t)ks * KSTRIDE + (size_t)(tm * 3 + tn) * TILE_F;
#pragma unroll
    for (int i = 0; i < 4; ++i) {
        int lr0 = wm * 64 + i * 16 + quad * 4;
#pragma unroll
        for (int j = 0; j < 4; ++j) {
            int lc = wn * 64 + j * 16 + l15;
#pragma unroll
            for (int r = 0; r < 4; ++r)
                gp[(lr0 + r) * 128 + lc] = acc[i][j][r];
        }
    }

    // ---- epilogue 2: diag blocks emit norm^2 partials (row == col elems)
    if (diag) {
        if (wm == wn && (l15 >> 2) == quad) {
#pragma unroll
            for (int i = 0; i < 4; ++i)
                Dp[(size_t)ks * NR + tm * 128 + wm * 64 + i * 16 + l15] =
                    acc[i][i][l15 & 3];
        }
    } else {
        // ---- epilogue 3: transposed copy via padded LDS (main loop done,
        // sbuf free). tb stride 129 -> transposed reads are 2-way max.
        float* tb = (float*)sbuf;                 // 64 x 129 floats = 33 KB
        float* gpT = Gp9 + (size_t)ks * KSTRIDE + (size_t)(tn * 3 + tm) * TILE_F;
#pragma unroll
        for (int h = 0; h < 2; ++h) {
            __syncthreads();                      // tb free / prev half drained
            if (wm == h) {
#pragma unroll
                for (int i = 0; i < 4; ++i) {
                    int rr0 = i * 16 + quad * 4;  // row within half 0..63
#pragma unroll
                    for (int j = 0; j < 4; ++j) {
                        int cc = wn * 64 + j * 16 + l15;
#pragma unroll
                        for (int r = 0; r < 4; ++r)
                            tb[(rr0 + r) * 129 + cc] = acc[i][j][r];
                    }
                }
            }
            __syncthreads();
#pragma unroll
            for (int rep = 0; rep < 32; ++rep) {
                int idx = rep * 256 + tid;        // 8192 = 128 cols x 64 rows
                int c = idx >> 6;
                int r = idx & 63;
                gpT[c * 128 + h * 64 + r] = tb[r * 129 + c];
            }
        }
    }
}

// ---------------------------------------------------------------- kernel 2
// Single tail kernel: invn from Dp, per-row Dsum + 4 pair-slot terms, and
// last-block final reduction (no same-address atomic storm, no extra
// launches). Block a (384 thr): thread b owns column b -- ALL reads
// coalesced thanks to the 9-tile Gp9 layout.
__global__ __launch_bounds__(384) void k_tail(const float* __restrict__ Gp9,
                                              const float* __restrict__ Dp,
                                              float* __restrict__ rt,
                                              unsigned* __restrict__ ctr,
                                              float* __restrict__ out) {
    __shared__ float invn_sh[NR];
    __shared__ float sv[NR];
    __shared__ float wred[6];
    __shared__ bool amlast;

    const int tid  = threadIdx.x;
    const int lane = tid & 63;
    const int w    = tid >> 6;
    const int b    = tid;                 // 384 threads == NR columns
    const int a    = blockIdx.x;

    // phase A: inverse norms (Dp is tiny + L2/L3-resident; coalesced)
    float s2 = 0.f;
    const float* dp = Dp + b;
#pragma unroll 8
    for (int ks = 0; ks < KSPLIT; ++ks) s2 += dp[(size_t)ks * NR];
    invn_sh[b] = 1.f / fmaxf(sqrtf(s2), 1e-6f);
    __syncthreads();

    // phase B: row a of G = sum_ks Gp9 partials (ascending ks, same order
    // as the verified k_red -> bit-identical G values)
    const int pa = a >> 7, pb = b >> 7;
    const float* gbase = Gp9 + (size_t)(pa * 3 + pb) * TILE_F
                       + (size_t)(a & 127) * 128 + (b & 127);
    float gsum = 0.f;
#pragma unroll 8
    for (int ks = 0; ks < KSPLIT; ++ks) gsum += gbase[(size_t)ks * KSTRIDE];

    const float ia = invn_sh[a];
    const float s  = gsum * ia * invn_sh[b] * 10.0f;
    sv[b] = s;
    float e = ((b & 15) != (a & 15)) ? expf(s) : 0.f;
#pragma unroll
    for (int o = 32; o > 0; o >>= 1) e += __shfl_down(e, o);
    if (lane == 0) wred[w] = e;
    __syncthreads();

    if (tid == 0) {
        float Dsa = wred[0] + wred[1] + wred[2] + wred[3] + wred[4] + wred[5];
        int pr[4];
        if (a < 16)       { pr[0] = 192 + a; pr[1] = a + 16;  pr[2] = a + 192; pr[3] = a + 368; }
        else if (a < 192) { pr[0] = 192 + a; pr[1] = a + 16;  pr[2] = a + 192; pr[3] = a - 16; }
        else if (a < 368) { pr[0] = a - 192; pr[1] = a + 16;  pr[2] = a - 192; pr[3] = a - 16; }
        else              { pr[0] = a - 192; pr[1] = a - 368; pr[2] = a - 192; pr[3] = a - 16; }
        float t = 0.f;
#pragma unroll
        for (int sidx = 0; sidx < 4; ++sidx) {
            float num = sv[pr[sidx]];
            t += -num + logf(expf(num) + Dsa);
        }
        rt[a] = t;
        __threadfence();                          // publish rt[a] device-wide
        amlast = (atomicAdd(ctr, 1u) == (unsigned)(NR - 1));
    }
    __syncthreads();

    // last block sums the 384 per-row terms -> out
    if (amlast) {
        __threadfence();                          // acquire: see all rt[]
        float v = rt[tid];
#pragma unroll
        for (int o = 32; o > 0; o >>= 1) v += __shfl_down(v, o);
        if (lane == 0) wred[w] = v;
        __syncthreads();
        if (tid == 0)
            out[0] = (wred[0] + wred[1] + wred[2] + wred[3] + wred[4] + wred[5])
                     * (1.0f / 576.0f);
    }
}

// ---------------------------------------------------------------- launch
extern "C" void kernel_launch(void* const* d_in, const int* in_sizes, int n_in,
                              void* d_out, int out_size, void* d_ws, size_t ws_size,
                              hipStream_t stream) {
    const float* X = (const float*)d_in[0];
    const float* M = (const float*)d_in[1];
    float* out = (float*)d_out;

    char* ws = (char*)d_ws;
    float* Gp9 = (float*)ws;                                   // 75.5 MB
    float* Dp  = Gp9 + (size_t)KSPLIT * KSTRIDE;               // 196.6 KB
    float* rt  = Dp + (size_t)KSPLIT * NR;                     // 1.5 KB
    unsigned* ctr = (unsigned*)(rt + NR);

    k_gram<<<dim3(6 * KSPLIT), dim3(256), 0, stream>>>(X, M, Gp9, Dp, ctr);
    k_tail<<<dim3(NR), dim3(384), 0, stream>>>(Gp9, Dp, rt, ctr, out);
}